// Round 3
// baseline (91.005 us; speedup 1.0000x reference)
//
#include <hip/hip_runtime.h>
#include <hip/hip_bf16.h>

// Paged-KV index construction.
// out[b*P + p] = (p < ceil(len[b]/64)) ? req_to_token[pool[b], clip(start[b]+p*64)] >> 6 : 0
// Harness delivers all integer inputs as int32 and reads the int64 reference
// output back as int32 — so we write raw int32 values to d_out.

#define PAGE_SHIFT 6
#define PAGE_SIZE 64

__global__ void kv_indices_kernel(const int* __restrict__ req_to_token,
                                  const int* __restrict__ req_pool_indices,
                                  const int* __restrict__ page_kernel_lens,
                                  const int* __restrict__ kv_start_idx,
                                  int* __restrict__ out,
                                  int max_ctx, int max_num_pages, int total) {
    int idx = blockIdx.x * blockDim.x + threadIdx.x;
    if (idx >= total) return;
    int b = idx / max_num_pages;
    int p = idx - b * max_num_pages;

    int kv_start  = kv_start_idx[b];
    int len       = page_kernel_lens[b];
    int num_paged = (len + PAGE_SIZE - 1) >> PAGE_SHIFT;

    int off = kv_start + (p << PAGE_SHIFT);
    off = min(max(off, 0), max_ctx - 1);

    int row = req_pool_indices[b];
    int data = req_to_token[(long long)row * (long long)max_ctx + off];

    out[idx] = (p < num_paged) ? (data >> PAGE_SHIFT) : 0;
}

extern "C" void kernel_launch(void* const* d_in, const int* in_sizes, int n_in,
                              void* d_out, int out_size, void* d_ws, size_t ws_size,
                              hipStream_t stream) {
    const int* req_to_token     = (const int*)d_in[0];
    const int* req_pool_indices = (const int*)d_in[1];
    const int* page_kernel_lens = (const int*)d_in[2];
    const int* kv_start_idx     = (const int*)d_in[3];
    int*       out              = (int*)d_out;

    int batch         = in_sizes[1];                 // 256
    int max_num_pages = out_size / batch;            // 512
    int max_ctx       = max_num_pages * PAGE_SIZE;   // 32768
    int total         = out_size;                    // 131072

    int block = 256;
    int grid  = (total + block - 1) / block;
    kv_indices_kernel<<<grid, block, 0, stream>>>(
        req_to_token, req_pool_indices, page_kernel_lens, kv_start_idx,
        out, max_ctx, max_num_pages, total);
}